// Round 1
// baseline (217.609 us; speedup 1.0000x reference)
//
#include <hip/hip_runtime.h>
#include <math.h>

// Problem constants
#define B_   8
#define C_   512
#define NH_  8
#define HD_  64
#define NSP  1024            // H*W
#define M_   (B_*NSP)        // 8192 rows
#define NQKV 1536
#define SCALE_ 0.125f        // 1/sqrt(64)

typedef __attribute__((ext_vector_type(8))) __bf16 bf16x8;
typedef __attribute__((ext_vector_type(4))) float  f32x4;

__device__ __forceinline__ unsigned short f2bf(float f) {
  unsigned int u = __float_as_uint(f);
  u = u + 0x7fffu + ((u >> 16) & 1u);   // round-to-nearest-even
  return (unsigned short)(u >> 16);
}

// ---------------------------------------------------------------- LN stats
// block 256 = 32 n-lanes x 8 c-groups; one block handles 32 n of one image
__global__ void ln_stats_kernel(const float* __restrict__ x,
                                float* __restrict__ mean,
                                float* __restrict__ rstd) {
  int tx = threadIdx.x & 31, ty = threadIdx.x >> 5;
  int bx = blockIdx.x;            // 0..255
  int b  = bx >> 5;               // 32 chunks per b
  int n0 = (bx & 31) * 32;
  const float* xp = x + (size_t)b * C_ * NSP + n0 + tx;
  float s = 0.f, s2 = 0.f;
  for (int c = ty; c < C_; c += 8) {
    float v = xp[(size_t)c * NSP];
    s += v; s2 += v * v;
  }
  __shared__ float sh_s[8][32], sh_s2[8][32];
  sh_s[ty][tx] = s; sh_s2[ty][tx] = s2;
  __syncthreads();
  if (ty == 0) {
    float S = 0.f, S2 = 0.f;
    for (int j = 0; j < 8; j++) { S += sh_s[j][tx]; S2 += sh_s2[j][tx]; }
    float mu  = S * (1.0f / C_);
    float var = S2 * (1.0f / C_) - mu * mu;
    mean[b * NSP + n0 + tx] = mu;
    rstd[b * NSP + n0 + tx] = rsqrtf(var + 1e-5f);
  }
}

// ------------------------------------------------- weight convert+transpose
// outputs wT[n][k] bf16 (so GEMM B-tile staging == A-tile staging pattern)
__global__ void conv_w_kernel(const float* __restrict__ wqkv,
                              const float* __restrict__ wproj,
                              unsigned short* __restrict__ wqkvT,
                              unsigned short* __restrict__ wprojT) {
  int i = blockIdx.x * 256 + threadIdx.x;   // grid covers exactly 1,048,576
  if (i < C_ * NQKV) {
    int k = i / NQKV, n = i - k * NQKV;
    wqkvT[n * C_ + k] = f2bf(wqkv[i]);
  } else {
    int j = i - C_ * NQKV;
    int k = j / C_, n = j - k * C_;
    wprojT[n * C_ + k] = f2bf(wproj[j]);
  }
}

// ------------------------------------------- LN apply + transpose to [m][c]
__global__ void ln_apply_kernel(const float* __restrict__ x,
                                const float* __restrict__ mean,
                                const float* __restrict__ rstd,
                                const float* __restrict__ gamma,
                                const float* __restrict__ beta,
                                unsigned short* __restrict__ xn) {
  __shared__ float tile[64][65];
  int b = blockIdx.z, n0 = blockIdx.y * 64, c0 = blockIdx.x * 64;
  int tx = threadIdx.x & 63, ty = threadIdx.x >> 6;   // ty in [0,4)
  const float* xp = x + ((size_t)b * C_ + c0) * NSP + n0;
  for (int i = ty; i < 64; i += 4)
    tile[i][tx] = xp[(size_t)i * NSP + tx];           // tile[c][n], coalesced
  __syncthreads();
  float g = gamma[c0 + tx], be = beta[c0 + tx];       // now tx = c-offset
  unsigned short* op = xn + ((size_t)(b * NSP + n0)) * C_ + c0 + tx;
  for (int i = ty; i < 64; i += 4) {                  // i = n-offset
    float mu = mean[b * NSP + n0 + i], rs = rstd[b * NSP + n0 + i];
    float v = (tile[tx][i] - mu) * rs * g + be;
    op[(size_t)i * C_] = f2bf(v);                     // coalesced bf16 write
  }
}

// ----------------------------------------------------------------- GEMM
// C[M,NW] = A[M,512] @ B[512,NW] + bias;  A row-major bf16, Bt = B^T row-major
// bf16. 128x128 block tile, BK=32, 4 waves each 64x64 (4x4 MFMA 16x16x32).
// EPI=0: bf16 row-major out.  EPI=1: fp32 out transposed to out[b][c][n].
template<int NW, int EPI>
__global__ __launch_bounds__(256) void gemm_kernel(
    const unsigned short* __restrict__ A,
    const unsigned short* __restrict__ Bt,
    const float* __restrict__ bias,
    void* __restrict__ outp) {
  __shared__ __align__(16) char smem[20480];
  unsigned short* As = (unsigned short*)smem;            // [128][40] pad
  unsigned short* Bs = (unsigned short*)(smem + 10240);  // [128][40]
  int tid = threadIdx.x;
  int wave = tid >> 6, lane = tid & 63, quad = lane >> 4, l15 = lane & 15;
  int n0 = blockIdx.x * 128, m0 = blockIdx.y * 128;
  int mrow = (wave >> 1) * 64, ncol = (wave & 1) * 64;
  f32x4 acc[4][4] = {};
  for (int k0 = 0; k0 < 512; k0 += 32) {
    if (k0) __syncthreads();
    for (int i = 0; i < 2; i++) {       // stage A tile: 16B chunks
      int cidx = tid + 256 * i;
      int row = cidx >> 2, kg = cidx & 3;
      *(uint4*)(As + row * 40 + kg * 8) =
          *(const uint4*)(A + (size_t)(m0 + row) * 512 + k0 + kg * 8);
    }
    for (int i = 0; i < 2; i++) {       // stage Bt tile (same pattern)
      int cidx = tid + 256 * i;
      int row = cidx >> 2, kg = cidx & 3;
      *(uint4*)(Bs + row * 40 + kg * 8) =
          *(const uint4*)(Bt + (size_t)(n0 + row) * 512 + k0 + kg * 8);
    }
    __syncthreads();
    bf16x8 a[4], bb[4];
    for (int mt = 0; mt < 4; mt++)
      a[mt] = *(const bf16x8*)(As + (mrow + mt * 16 + l15) * 40 + quad * 8);
    for (int nt = 0; nt < 4; nt++)
      bb[nt] = *(const bf16x8*)(Bs + (ncol + nt * 16 + l15) * 40 + quad * 8);
    for (int mt = 0; mt < 4; mt++)
      for (int nt = 0; nt < 4; nt++)
        acc[mt][nt] = __builtin_amdgcn_mfma_f32_16x16x32_bf16(
            a[mt], bb[nt], acc[mt][nt], 0, 0, 0);
  }
  if (EPI == 0) {
    unsigned short* O = (unsigned short*)outp;
    for (int mt = 0; mt < 4; mt++)
      for (int nt = 0; nt < 4; nt++)
        for (int r = 0; r < 4; r++) {
          int row = m0 + mrow + mt * 16 + quad * 4 + r;
          int col = n0 + ncol + nt * 16 + l15;
          O[(size_t)row * NW + col] = f2bf(acc[mt][nt][r] + bias[col]);
        }
  } else {
    // transpose epilogue: out[b][c][n] fp32, coalesced via LDS bounce
    __syncthreads();                       // staging reads all done
    float* buf = (float*)smem + wave * (64 * 17);   // [64][17] per wave
    float* O = (float*)outp;
    int b = m0 >> 10;
    int nbase = m0 & 1023;
    for (int nc = 0; nc < 4; nc++) {
      for (int mt = 0; mt < 4; mt++)
        for (int r = 0; r < 4; r++) {
          int col = n0 + ncol + nc * 16 + l15;
          buf[(mt * 16 + quad * 4 + r) * 17 + l15] = acc[mt][nc][r] + bias[col];
        }
      __syncthreads();
      for (int cc = 0; cc < 16; cc++) {
        int c = n0 + ncol + nc * 16 + cc;
        O[((size_t)b * C_ + c) * NSP + nbase + mrow + lane] = buf[lane * 17 + cc];
      }
      __syncthreads();
    }
  }
}

// ------------------------------------------------------- flash attention
// block = (b, h, 128 q-rows), 4 waves x 32 q-rows. K/V streamed in 64-blocks.
__global__ __launch_bounds__(256) void attn_kernel(
    const unsigned short* __restrict__ qkv, unsigned short* __restrict__ o_ws) {
  __shared__ __align__(16) unsigned short Qs[128][72];
  __shared__ __align__(16) unsigned short Ks[64][72];
  __shared__ __align__(16) unsigned short Vts[64][72];   // [d][key]
  __shared__ __align__(16) unsigned short Ps[4][32][72];
  int tid = threadIdx.x;
  int wave = tid >> 6, lane = tid & 63, quad = lane >> 4, l15 = lane & 15;
  int b = blockIdx.x >> 3, h = blockIdx.x & 7;
  int q0 = blockIdx.y * 128;
  // stage Q (128 x 64 bf16)
  for (int i = 0; i < 4; i++) {
    int cidx = tid + 256 * i;
    int row = cidx >> 3, dg = cidx & 7;
    *(uint4*)(&Qs[row][dg * 8]) = *(const uint4*)(
        qkv + ((size_t)(b * NSP + q0 + row)) * NQKV + h * 64 + dg * 8);
  }
  f32x4 o[2][4] = {};
  float mrow[2][4], lrow[2][4];
  for (int mt = 0; mt < 2; mt++)
    for (int r = 0; r < 4; r++) { mrow[mt][r] = -INFINITY; lrow[mt][r] = 0.f; }
  __syncthreads();
  for (int kb = 0; kb < NSP / 64; kb++) {
    int k0 = kb * 64;
    if (kb) __syncthreads();           // protect Ks/Vts reuse
    for (int i = 0; i < 2; i++) {      // stage K
      int cidx = tid + 256 * i;
      int row = cidx >> 3, dg = cidx & 7;
      *(uint4*)(&Ks[row][dg * 8]) = *(const uint4*)(
          qkv + ((size_t)(b * NSP + k0 + row)) * NQKV + 512 + h * 64 + dg * 8);
    }
    for (int i = 0; i < 16; i++) {     // stage V transposed
      int e = tid + 256 * i;
      int key = e >> 6, d = e & 63;
      Vts[d][key] = qkv[((size_t)(b * NSP + k0 + key)) * NQKV + 1024 + h * 64 + d];
    }
    __syncthreads();
    // S = Q K^T  (32 q-rows x 64 keys per wave)
    bf16x8 aq[2][2], bk[4][2];
    for (int mt = 0; mt < 2; mt++)
      for (int ks = 0; ks < 2; ks++)
        aq[mt][ks] = *(const bf16x8*)(&Qs[wave * 32 + mt * 16 + l15][ks * 32 + quad * 8]);
    for (int nt = 0; nt < 4; nt++)
      for (int ks = 0; ks < 2; ks++)
        bk[nt][ks] = *(const bf16x8*)(&Ks[nt * 16 + l15][ks * 32 + quad * 8]);
    f32x4 s[2][4] = {};
    for (int mt = 0; mt < 2; mt++)
      for (int nt = 0; nt < 4; nt++)
        for (int ks = 0; ks < 2; ks++)
          s[mt][nt] = __builtin_amdgcn_mfma_f32_16x16x32_bf16(
              aq[mt][ks], bk[nt][ks], s[mt][nt], 0, 0, 0);
    // online softmax (rows live in 16-lane groups; shfl width 16)
    for (int mt = 0; mt < 2; mt++)
      for (int r = 0; r < 4; r++) {
        float mx = s[mt][0][r];
        for (int nt = 1; nt < 4; nt++) mx = fmaxf(mx, s[mt][nt][r]);
        mx *= SCALE_;
        for (int off = 1; off < 16; off <<= 1) mx = fmaxf(mx, __shfl_xor(mx, off, 16));
        float mn = fmaxf(mrow[mt][r], mx);
        float alpha = __expf(mrow[mt][r] - mn);
        mrow[mt][r] = mn;
        float ps = 0.f;
        for (int nt = 0; nt < 4; nt++) {
          float p = __expf(s[mt][nt][r] * SCALE_ - mn);
          s[mt][nt][r] = p;
          ps += p;
        }
        for (int off = 1; off < 16; off <<= 1) ps += __shfl_xor(ps, off, 16);
        lrow[mt][r] = lrow[mt][r] * alpha + ps;
        for (int nt = 0; nt < 4; nt++) o[mt][nt][r] *= alpha;
      }
    // P: C-layout regs -> LDS -> A-layout frags
    for (int mt = 0; mt < 2; mt++)
      for (int nt = 0; nt < 4; nt++)
        for (int r = 0; r < 4; r++)
          Ps[wave][mt * 16 + quad * 4 + r][nt * 16 + l15] = f2bf(s[mt][nt][r]);
    __syncthreads();
    bf16x8 ap[2][2], bv[4][2];
    for (int mt = 0; mt < 2; mt++)
      for (int ks = 0; ks < 2; ks++)
        ap[mt][ks] = *(const bf16x8*)(&Ps[wave][mt * 16 + l15][ks * 32 + quad * 8]);
    for (int nt = 0; nt < 4; nt++)
      for (int ks = 0; ks < 2; ks++)
        bv[nt][ks] = *(const bf16x8*)(&Vts[nt * 16 + l15][ks * 32 + quad * 8]);
    for (int mt = 0; mt < 2; mt++)
      for (int nt = 0; nt < 4; nt++)
        for (int ks = 0; ks < 2; ks++)
          o[mt][nt] = __builtin_amdgcn_mfma_f32_16x16x32_bf16(
              ap[mt][ks], bv[nt][ks], o[mt][nt], 0, 0, 0);
  }
  // epilogue: O /= l, write bf16 o[b*n][h*64+d]
  for (int mt = 0; mt < 2; mt++)
    for (int r = 0; r < 4; r++) {
      float inv = 1.f / lrow[mt][r];
      int row = q0 + wave * 32 + mt * 16 + quad * 4 + r;
      for (int nt = 0; nt < 4; nt++) {
        int d = nt * 16 + l15;
        o_ws[((size_t)(b * NSP + row)) * C_ + h * 64 + d] = f2bf(o[mt][nt][r] * inv);
      }
    }
}

// ------------------------------------------------------------------ launch
extern "C" void kernel_launch(void* const* d_in, const int* in_sizes, int n_in,
                              void* d_out, int out_size, void* d_ws, size_t ws_size,
                              hipStream_t stream) {
  const float* x     = (const float*)d_in[0];
  const float* gamma = (const float*)d_in[1];
  const float* beta  = (const float*)d_in[2];
  const float* wqkv  = (const float*)d_in[3];
  const float* bqkv  = (const float*)d_in[4];
  const float* wproj = (const float*)d_in[5];
  const float* bproj = (const float*)d_in[6];
  char* ws = (char*)d_ws;
  // workspace layout (all 16B aligned), total ~35.7 MB
  float*          mean    = (float*)ws;                          //  32 KB
  float*          rstd    = (float*)(ws + 32768);                //  32 KB
  unsigned short* wqkvT   = (unsigned short*)(ws + 65536);       // 1.5 MB
  unsigned short* wprojT  = (unsigned short*)(ws + 1638400);     // 0.5 MB
  unsigned short* qkv_bf  = (unsigned short*)(ws + 2162688);     //  24 MB
  unsigned short* xn_bf   = (unsigned short*)(ws + 27328512);    //   8 MB (reused as o)
  float* out = (float*)d_out;

  ln_stats_kernel<<<256, 256, 0, stream>>>(x, mean, rstd);
  conv_w_kernel<<<4096, 256, 0, stream>>>(wqkv, wproj, wqkvT, wprojT);
  ln_apply_kernel<<<dim3(8, 16, 8), 256, 0, stream>>>(x, mean, rstd, gamma, beta, xn_bf);
  gemm_kernel<NQKV, 0><<<dim3(NQKV / 128, M_ / 128), 256, 0, stream>>>(
      xn_bf, wqkvT, bqkv, (void*)qkv_bf);
  attn_kernel<<<dim3(B_ * NH_, NSP / 128), 256, 0, stream>>>(qkv_bf, xn_bf);
  gemm_kernel<C_, 1><<<dim3(C_ / 128, M_ / 128), 256, 0, stream>>>(
      xn_bf, wprojT, bproj, (void*)out);
}

// Round 2
// 198.012 us; speedup vs baseline: 1.0990x; 1.0990x over previous
//
#include <hip/hip_runtime.h>
#include <math.h>

// Problem constants
#define B_   8
#define C_   512
#define NH_  8
#define HD_  64
#define NSP  1024            // H*W
#define M_   (B_*NSP)        // 8192 rows
#define NQKV 1536
#define SCALE_ 0.125f        // 1/sqrt(64)

typedef __attribute__((ext_vector_type(8))) __bf16 bf16x8;
typedef __attribute__((ext_vector_type(4))) float  f32x4;

__device__ __forceinline__ unsigned short f2bf(float f) {
  unsigned int u = __float_as_uint(f);
  u = u + 0x7fffu + ((u >> 16) & 1u);   // round-to-nearest-even
  return (unsigned short)(u >> 16);
}

// async global->LDS 16B (dest = wave-uniform base + lane*16)
__device__ __forceinline__ void async16(const unsigned short* g, unsigned short* l) {
  __builtin_amdgcn_global_load_lds(
      (const __attribute__((address_space(1))) void*)g,
      (__attribute__((address_space(3))) void*)l, 16, 0, 0);
}

// ---------------------------------------------------------------- LN stats
__global__ void ln_stats_kernel(const float* __restrict__ x,
                                float* __restrict__ mean,
                                float* __restrict__ rstd) {
  int tx = threadIdx.x & 31, ty = threadIdx.x >> 5;
  int bx = blockIdx.x;
  int b  = bx >> 5;
  int n0 = (bx & 31) * 32;
  const float* xp = x + (size_t)b * C_ * NSP + n0 + tx;
  float s = 0.f, s2 = 0.f;
  for (int c = ty; c < C_; c += 8) {
    float v = xp[(size_t)c * NSP];
    s += v; s2 += v * v;
  }
  __shared__ float sh_s[8][32], sh_s2[8][32];
  sh_s[ty][tx] = s; sh_s2[ty][tx] = s2;
  __syncthreads();
  if (ty == 0) {
    float S = 0.f, S2 = 0.f;
    for (int j = 0; j < 8; j++) { S += sh_s[j][tx]; S2 += sh_s2[j][tx]; }
    float mu  = S * (1.0f / C_);
    float var = S2 * (1.0f / C_) - mu * mu;
    mean[b * NSP + n0 + tx] = mu;
    rstd[b * NSP + n0 + tx] = rsqrtf(var + 1e-5f);
  }
}

// ------------------------------------------------- weight convert+transpose
__global__ void conv_w_kernel(const float* __restrict__ wqkv,
                              const float* __restrict__ wproj,
                              unsigned short* __restrict__ wqkvT,
                              unsigned short* __restrict__ wprojT) {
  int i = blockIdx.x * 256 + threadIdx.x;
  if (i < C_ * NQKV) {
    int k = i / NQKV, n = i - k * NQKV;
    wqkvT[n * C_ + k] = f2bf(wqkv[i]);
  } else {
    int j = i - C_ * NQKV;
    int k = j / C_, n = j - k * C_;
    wprojT[n * C_ + k] = f2bf(wproj[j]);
  }
}

// ------------------------------------------- LN apply + transpose to [m][c]
__global__ void ln_apply_kernel(const float* __restrict__ x,
                                const float* __restrict__ mean,
                                const float* __restrict__ rstd,
                                const float* __restrict__ gamma,
                                const float* __restrict__ beta,
                                unsigned short* __restrict__ xn) {
  __shared__ float tile[64][65];
  int b = blockIdx.z, n0 = blockIdx.y * 64, c0 = blockIdx.x * 64;
  int tx = threadIdx.x & 63, ty = threadIdx.x >> 6;
  const float* xp = x + ((size_t)b * C_ + c0) * NSP + n0;
  for (int i = ty; i < 64; i += 4)
    tile[i][tx] = xp[(size_t)i * NSP + tx];
  __syncthreads();
  float g = gamma[c0 + tx], be = beta[c0 + tx];
  unsigned short* op = xn + ((size_t)(b * NSP + n0)) * C_ + c0 + tx;
  for (int i = ty; i < 64; i += 4) {
    float mu = mean[b * NSP + n0 + i], rs = rstd[b * NSP + n0 + i];
    float v = (tile[tx][i] - mu) * rs * g + be;
    op[(size_t)i * C_] = f2bf(v);
  }
}

// ----------------------------------------------------------------- GEMM
// C[M,NW] = A[M,512] @ B[512,NW] + bias. m97-style: unpadded [128][32] tiles,
// global_load_lds width-16, 4 waves x (4x4) 16x16x32 MFMA.
// MODE 1: fp32 out transposed to out0[b][c][n]   (proj)
// MODE 2: col<1024 -> bf16 row-major stride 1024 into out0 (Q,K);
//         col>=1024 -> bf16 transposed into out1 = vt[(b*512+c-1024)*1024+n] (V)
template<int NW, int MODE>
__global__ __launch_bounds__(256) void gemm_kernel(
    const unsigned short* __restrict__ A,
    const unsigned short* __restrict__ Bt,
    const float* __restrict__ bias,
    void* __restrict__ out0, unsigned short* __restrict__ out1) {
  __shared__ __align__(16) char smem[20480];
  unsigned short* As = (unsigned short*)smem;           // [128][32]
  unsigned short* Bs = (unsigned short*)(smem + 8192);  // [128][32]
  int tid = threadIdx.x;
  int wave = tid >> 6, lane = tid & 63, quad = lane >> 4, l15 = lane & 15;
  int n0 = blockIdx.x * 128, m0 = blockIdx.y * 128;
  int mrow = (wave >> 1) * 64, ncol = (wave & 1) * 64;
  int srow = lane >> 2, schunk = (lane & 3) * 8;   // staging: 16 rows/wave-load
  f32x4 acc[4][4] = {};
  for (int k0 = 0; k0 < 512; k0 += 32) {
    if (k0) __syncthreads();
#pragma unroll
    for (int j = 0; j < 2; j++) {
      int r0 = (wave + 4 * j) * 16;
      async16(A + (size_t)(m0 + r0 + srow) * 512 + k0 + schunk, As + r0 * 32 + lane * 8);
      async16(Bt + (size_t)(n0 + r0 + srow) * 512 + k0 + schunk, Bs + r0 * 32 + lane * 8);
    }
    __syncthreads();
    bf16x8 a[4], bb[4];
#pragma unroll
    for (int mt = 0; mt < 4; mt++)
      a[mt] = *(const bf16x8*)(As + (mrow + mt * 16 + l15) * 32 + quad * 8);
#pragma unroll
    for (int nt = 0; nt < 4; nt++)
      bb[nt] = *(const bf16x8*)(Bs + (ncol + nt * 16 + l15) * 32 + quad * 8);
#pragma unroll
    for (int mt = 0; mt < 4; mt++)
#pragma unroll
      for (int nt = 0; nt < 4; nt++)
        acc[mt][nt] = __builtin_amdgcn_mfma_f32_16x16x32_bf16(
            a[mt], bb[nt], acc[mt][nt], 0, 0, 0);
  }
  if (MODE == 2 && n0 < 1024) {
    unsigned short* O = (unsigned short*)out0;
#pragma unroll
    for (int mt = 0; mt < 4; mt++)
#pragma unroll
      for (int nt = 0; nt < 4; nt++)
#pragma unroll
        for (int r = 0; r < 4; r++) {
          int row = m0 + mrow + mt * 16 + quad * 4 + r;
          int col = n0 + ncol + nt * 16 + l15;
          O[(size_t)row * 1024 + col] = f2bf(acc[mt][nt][r] + bias[col]);
        }
  } else if (MODE == 2) {
    // V blocks: bf16 transposed into vt[(b*512 + (col-1024))*1024 + n]
    __syncthreads();
    unsigned short* buf = (unsigned short*)smem + wave * (64 * 17);
    int b = m0 >> 10, nbase = m0 & 1023;
    for (int nc = 0; nc < 4; nc++) {
#pragma unroll
      for (int mt = 0; mt < 4; mt++)
#pragma unroll
        for (int r = 0; r < 4; r++) {
          int col = n0 + ncol + nc * 16 + l15;
          buf[(mt * 16 + quad * 4 + r) * 17 + l15] = f2bf(acc[mt][nc][r] + bias[col]);
        }
      __syncthreads();
      for (int cc = 0; cc < 16; cc++) {
        int crel = n0 - 1024 + ncol + nc * 16 + cc;
        out1[((size_t)b * C_ + crel) * NSP + nbase + mrow + lane] = buf[lane * 17 + cc];
      }
      __syncthreads();
    }
  } else {
    // MODE 1: fp32 transposed epilogue out0[b][c][n]
    __syncthreads();
    float* buf = (float*)smem + wave * (64 * 17);
    float* O = (float*)out0;
    int b = m0 >> 10, nbase = m0 & 1023;
    for (int nc = 0; nc < 4; nc++) {
#pragma unroll
      for (int mt = 0; mt < 4; mt++)
#pragma unroll
        for (int r = 0; r < 4; r++) {
          int col = n0 + ncol + nc * 16 + l15;
          buf[(mt * 16 + quad * 4 + r) * 17 + l15] = acc[mt][nc][r] + bias[col];
        }
      __syncthreads();
      for (int cc = 0; cc < 16; cc++) {
        int c = n0 + ncol + nc * 16 + cc;
        O[((size_t)b * C_ + c) * NSP + nbase + mrow + lane] = buf[lane * 17 + cc];
      }
      __syncthreads();
    }
  }
}

// ------------------------------------------------------- flash attention
// qk: [b*n][1024] bf16 (Q cols 0-511, K cols 512-1023); vt: [b*512+h*64+d][n]
// block = (b,h, 128 q-rows); 4 waves x 32 q-rows. S computed TRANSPOSED
// (S^T = K.Q^T) so softmax rows sit on fixed l15 lanes: 2-shfl reductions,
// b64 P-writes. O accumulated transposed (O^T = V^T.P^T).
__global__ __launch_bounds__(256, 4) void attn_kernel(
    const unsigned short* __restrict__ qk,
    const unsigned short* __restrict__ vt,
    unsigned short* __restrict__ o_ws) {
  __shared__ __align__(16) unsigned short Ks[64][72];
  __shared__ __align__(16) unsigned short Vts[64][72];   // [d][key]
  __shared__ __align__(16) unsigned short Ps[4][32][72]; // per-wave P[m][n]
  int tid = threadIdx.x;
  int wave = tid >> 6, lane = tid & 63, quad = lane >> 4, l15 = lane & 15;
  int b = blockIdx.x >> 3, h = blockIdx.x & 7;
  int q0 = blockIdx.y * 128;
  // Q fragments straight from global (B-operand layout: rows m, k=d)
  bf16x8 bq[2][2];
#pragma unroll
  for (int mt = 0; mt < 2; mt++)
#pragma unroll
    for (int ks = 0; ks < 2; ks++)
      bq[mt][ks] = *(const bf16x8*)(
          qk + (size_t)(b * NSP + q0 + wave * 32 + mt * 16 + l15) * 1024 +
          h * 64 + ks * 32 + quad * 8);
  f32x4 ot[4][2] = {};     // O^T: [d = dt*16+quad*4+r][m = mt*16+l15]
  float mrow[2] = {-INFINITY, -INFINITY}, lrow[2] = {0.f, 0.f};
  for (int kb = 0; kb < NSP / 64; kb++) {
    int k0 = kb * 64;
    if (kb) __syncthreads();
#pragma unroll
    for (int j = 0; j < 2; j++) {     // stage K tile [key][d]
      int idx = tid + 256 * j, row = idx >> 3, c = (idx & 7) * 8;
      *(uint4*)(&Ks[row][c]) = *(const uint4*)(
          qk + (size_t)(b * NSP + k0 + row) * 1024 + 512 + h * 64 + c);
    }
#pragma unroll
    for (int j = 0; j < 2; j++) {     // stage V^T tile [d][key] — vectorized
      int idx = tid + 256 * j, row = idx >> 3, c = (idx & 7) * 8;
      *(uint4*)(&Vts[row][c]) = *(const uint4*)(
          vt + ((size_t)(b * C_ + h * 64 + row)) * NSP + k0 + c);
    }
    __syncthreads();
    // S^T[n][m] = mfma(A=K rows n, B=Q rows m)
    bf16x8 ak[4][2];
#pragma unroll
    for (int n4 = 0; n4 < 4; n4++)
#pragma unroll
      for (int ks = 0; ks < 2; ks++)
        ak[n4][ks] = *(const bf16x8*)(&Ks[n4 * 16 + l15][ks * 32 + quad * 8]);
    f32x4 s[4][2] = {};
#pragma unroll
    for (int n4 = 0; n4 < 4; n4++)
#pragma unroll
      for (int mt = 0; mt < 2; mt++)
#pragma unroll
        for (int ks = 0; ks < 2; ks++)
          s[n4][mt] = __builtin_amdgcn_mfma_f32_16x16x32_bf16(
              ak[n4][ks], bq[mt][ks], s[n4][mt], 0, 0, 0);
    // online softmax: row m = mt*16+l15; n elements = (n4, quad, r)
#pragma unroll
    for (int mt = 0; mt < 2; mt++) {
      float mx = s[0][mt][0];
#pragma unroll
      for (int n4 = 0; n4 < 4; n4++)
#pragma unroll
        for (int r = 0; r < 4; r++) mx = fmaxf(mx, s[n4][mt][r]);
      mx = fmaxf(mx, __shfl_xor(mx, 16));
      mx = fmaxf(mx, __shfl_xor(mx, 32));
      mx *= SCALE_;
      float mn = fmaxf(mrow[mt], mx);
      float alpha = __expf(mrow[mt] - mn);
      mrow[mt] = mn;
      float ps = 0.f;
#pragma unroll
      for (int n4 = 0; n4 < 4; n4++)
#pragma unroll
        for (int r = 0; r < 4; r++) {
          float p = __expf(fmaf(s[n4][mt][r], SCALE_, -mn));
          s[n4][mt][r] = p;
          ps += p;
        }
      ps += __shfl_xor(ps, 16);
      ps += __shfl_xor(ps, 32);
      lrow[mt] = lrow[mt] * alpha + ps;
#pragma unroll
      for (int dt = 0; dt < 4; dt++) ot[dt][mt] *= alpha;
    }
    // P spill: 4 consecutive n per lane -> b64 writes (wave-private, no barrier)
#pragma unroll
    for (int mt = 0; mt < 2; mt++)
#pragma unroll
      for (int n4 = 0; n4 < 4; n4++) {
        unsigned int lo = (unsigned int)f2bf(s[n4][mt][0]) |
                          ((unsigned int)f2bf(s[n4][mt][1]) << 16);
        unsigned int hi = (unsigned int)f2bf(s[n4][mt][2]) |
                          ((unsigned int)f2bf(s[n4][mt][3]) << 16);
        *(uint2*)(&Ps[wave][mt * 16 + l15][n4 * 16 + quad * 4]) = make_uint2(lo, hi);
      }
    // O^T += mfma(A=V^T rows d, B=P rows m)
    bf16x8 av[4][2], bp[2][2];
#pragma unroll
    for (int dt = 0; dt < 4; dt++)
#pragma unroll
      for (int ks = 0; ks < 2; ks++)
        av[dt][ks] = *(const bf16x8*)(&Vts[dt * 16 + l15][ks * 32 + quad * 8]);
#pragma unroll
    for (int mt = 0; mt < 2; mt++)
#pragma unroll
      for (int ks = 0; ks < 2; ks++)
        bp[mt][ks] = *(const bf16x8*)(&Ps[wave][mt * 16 + l15][ks * 32 + quad * 8]);
#pragma unroll
    for (int dt = 0; dt < 4; dt++)
#pragma unroll
      for (int mt = 0; mt < 2; mt++)
#pragma unroll
        for (int ks = 0; ks < 2; ks++)
          ot[dt][mt] = __builtin_amdgcn_mfma_f32_16x16x32_bf16(
              av[dt][ks], bp[mt][ks], ot[dt][mt], 0, 0, 0);
  }
  // epilogue: o_ws[(b*N+m)*512 + h*64 + d] = O^T[d][m] / l[m]
#pragma unroll
  for (int mt = 0; mt < 2; mt++) {
    float inv = 1.f / lrow[mt];
    size_t rowoff = (size_t)(b * NSP + q0 + wave * 32 + mt * 16 + l15) * 512 + h * 64;
#pragma unroll
    for (int dt = 0; dt < 4; dt++) {
      unsigned int lo = (unsigned int)f2bf(ot[dt][mt][0] * inv) |
                        ((unsigned int)f2bf(ot[dt][mt][1] * inv) << 16);
      unsigned int hi = (unsigned int)f2bf(ot[dt][mt][2] * inv) |
                        ((unsigned int)f2bf(ot[dt][mt][3] * inv) << 16);
      *(uint2*)(o_ws + rowoff + dt * 16 + quad * 4) = make_uint2(lo, hi);
    }
  }
}

// ------------------------------------------------------------------ launch
extern "C" void kernel_launch(void* const* d_in, const int* in_sizes, int n_in,
                              void* d_out, int out_size, void* d_ws, size_t ws_size,
                              hipStream_t stream) {
  const float* x     = (const float*)d_in[0];
  const float* gamma = (const float*)d_in[1];
  const float* beta  = (const float*)d_in[2];
  const float* wqkv  = (const float*)d_in[3];
  const float* bqkv  = (const float*)d_in[4];
  const float* wproj = (const float*)d_in[5];
  const float* bproj = (const float*)d_in[6];
  char* ws = (char*)d_ws;
  // workspace layout (35.7 MB total; o_bf aliases xn_bf — xn dead after QKV GEMM)
  float*          mean   = (float*)ws;                        //  32 KB
  float*          rstd   = (float*)(ws + 32768);              //  32 KB
  unsigned short* wqkvT  = (unsigned short*)(ws + 65536);     // 1.5 MB
  unsigned short* wprojT = (unsigned short*)(ws + 1638400);   // 0.5 MB
  unsigned short* qk_bf  = (unsigned short*)(ws + 2162688);   //  16 MB [m][1024]
  unsigned short* vt_bf  = (unsigned short*)(ws + 18939904);  //   8 MB [b*512+c][n]
  unsigned short* xn_bf  = (unsigned short*)(ws + 27328512);  //   8 MB
  unsigned short* o_bf   = xn_bf;                             //   8 MB (alias)
  float* out = (float*)d_out;

  ln_stats_kernel<<<256, 256, 0, stream>>>(x, mean, rstd);
  conv_w_kernel<<<4096, 256, 0, stream>>>(wqkv, wproj, wqkvT, wprojT);
  ln_apply_kernel<<<dim3(8, 16, 8), 256, 0, stream>>>(x, mean, rstd, gamma, beta, xn_bf);
  gemm_kernel<NQKV, 2><<<dim3(NQKV / 128, M_ / 128), 256, 0, stream>>>(
      xn_bf, wqkvT, bqkv, (void*)qk_bf, vt_bf);
  attn_kernel<<<dim3(B_ * NH_, NSP / 128), 256, 0, stream>>>(qk_bf, vt_bf, o_bf);
  gemm_kernel<C_, 1><<<dim3(C_ / 128, M_ / 128), 256, 0, stream>>>(
      o_bf, wprojT, bproj, (void*)out, nullptr);
}

// Round 3
// 195.777 us; speedup vs baseline: 1.1115x; 1.0114x over previous
//
#include <hip/hip_runtime.h>
#include <math.h>

// Problem constants
#define B_   8
#define C_   512
#define NH_  8
#define HD_  64
#define NSP  1024            // H*W
#define M_   (B_*NSP)        // 8192 rows
#define NQKV 1536
#define SCALE_ 0.125f        // 1/sqrt(64)
#define S2L_  0.18033688f    // SCALE_ * log2(e)

typedef __attribute__((ext_vector_type(8))) __bf16 bf16x8;
typedef __attribute__((ext_vector_type(4))) float  f32x4;

__device__ __forceinline__ unsigned short f2bf(float f) {
  unsigned int u = __float_as_uint(f);
  u = u + 0x7fffu + ((u >> 16) & 1u);   // round-to-nearest-even
  return (unsigned short)(u >> 16);
}

// async global->LDS 16B (dest = wave-uniform base + lane*16)
__device__ __forceinline__ void async16(const unsigned short* g, unsigned short* l) {
  __builtin_amdgcn_global_load_lds(
      (const __attribute__((address_space(1))) void*)g,
      (__attribute__((address_space(3))) void*)l, 16, 0, 0);
}

// ---------------------------------------------------------------- LN stats
__global__ void ln_stats_kernel(const float* __restrict__ x,
                                float* __restrict__ mean,
                                float* __restrict__ rstd) {
  int tx = threadIdx.x & 31, ty = threadIdx.x >> 5;
  int bx = blockIdx.x;
  int b  = bx >> 5;
  int n0 = (bx & 31) * 32;
  const float* xp = x + (size_t)b * C_ * NSP + n0 + tx;
  float s = 0.f, s2 = 0.f;
  for (int c = ty; c < C_; c += 8) {
    float v = xp[(size_t)c * NSP];
    s += v; s2 += v * v;
  }
  __shared__ float sh_s[8][32], sh_s2[8][32];
  sh_s[ty][tx] = s; sh_s2[ty][tx] = s2;
  __syncthreads();
  if (ty == 0) {
    float S = 0.f, S2 = 0.f;
    for (int j = 0; j < 8; j++) { S += sh_s[j][tx]; S2 += sh_s2[j][tx]; }
    float mu  = S * (1.0f / C_);
    float var = S2 * (1.0f / C_) - mu * mu;
    mean[b * NSP + n0 + tx] = mu;
    rstd[b * NSP + n0 + tx] = rsqrtf(var + 1e-5f);
  }
}

// ------------------------------------------------- weight convert+transpose
__global__ void conv_w_kernel(const float* __restrict__ wqkv,
                              const float* __restrict__ wproj,
                              unsigned short* __restrict__ wqkvT,
                              unsigned short* __restrict__ wprojT) {
  int i = blockIdx.x * 256 + threadIdx.x;
  if (i < C_ * NQKV) {
    int k = i / NQKV, n = i - k * NQKV;
    wqkvT[n * C_ + k] = f2bf(wqkv[i]);
  } else {
    int j = i - C_ * NQKV;
    int k = j / C_, n = j - k * C_;
    wprojT[n * C_ + k] = f2bf(wproj[j]);
  }
}

// ------------------------------------------- LN apply + transpose to [m][c]
__global__ void ln_apply_kernel(const float* __restrict__ x,
                                const float* __restrict__ mean,
                                const float* __restrict__ rstd,
                                const float* __restrict__ gamma,
                                const float* __restrict__ beta,
                                unsigned short* __restrict__ xn) {
  __shared__ float tile[64][65];
  int b = blockIdx.z, n0 = blockIdx.y * 64, c0 = blockIdx.x * 64;
  int tx = threadIdx.x & 63, ty = threadIdx.x >> 6;
  const float* xp = x + ((size_t)b * C_ + c0) * NSP + n0;
  for (int i = ty; i < 64; i += 4)
    tile[i][tx] = xp[(size_t)i * NSP + tx];
  __syncthreads();
  float g = gamma[c0 + tx], be = beta[c0 + tx];
  unsigned short* op = xn + ((size_t)(b * NSP + n0)) * C_ + c0 + tx;
  for (int i = ty; i < 4 * 16; i += 4) {
    float mu = mean[b * NSP + n0 + i], rs = rstd[b * NSP + n0 + i];
    float v = (tile[tx][i] - mu) * rs * g + be;
    op[(size_t)i * C_] = f2bf(v);
  }
}

// ----------------------------------------------------------------- GEMM
// C[M,NW] = A[M,512] @ B[512,NW] + bias. m97-style: unpadded [128][32] tiles,
// global_load_lds width-16, 4 waves x (4x4) 16x16x32 MFMA.
// MODE 1: fp32 out transposed to out0[b][c][n]   (proj)
// MODE 2: col<1024 -> bf16 row-major stride 1024 into out0 (Q,K);
//         col>=1024 -> bf16 transposed into out1 = vt[(b*512+c-1024)*1024+n] (V)
template<int NW, int MODE>
__global__ __launch_bounds__(256) void gemm_kernel(
    const unsigned short* __restrict__ A,
    const unsigned short* __restrict__ Bt,
    const float* __restrict__ bias,
    void* __restrict__ out0, unsigned short* __restrict__ out1) {
  __shared__ __align__(16) char smem[20480];
  unsigned short* As = (unsigned short*)smem;           // [128][32]
  unsigned short* Bs = (unsigned short*)(smem + 8192);  // [128][32]
  int tid = threadIdx.x;
  int wave = tid >> 6, lane = tid & 63, quad = lane >> 4, l15 = lane & 15;
  int n0 = blockIdx.x * 128, m0 = blockIdx.y * 128;
  int mrow = (wave >> 1) * 64, ncol = (wave & 1) * 64;
  int srow = lane >> 2, schunk = (lane & 3) * 8;   // staging: 16 rows/wave-load
  f32x4 acc[4][4] = {};
  for (int k0 = 0; k0 < 512; k0 += 32) {
    if (k0) __syncthreads();
#pragma unroll
    for (int j = 0; j < 2; j++) {
      int r0 = (wave + 4 * j) * 16;
      async16(A + (size_t)(m0 + r0 + srow) * 512 + k0 + schunk, As + r0 * 32 + lane * 8);
      async16(Bt + (size_t)(n0 + r0 + srow) * 512 + k0 + schunk, Bs + r0 * 32 + lane * 8);
    }
    __syncthreads();
    bf16x8 a[4], bb[4];
#pragma unroll
    for (int mt = 0; mt < 4; mt++)
      a[mt] = *(const bf16x8*)(As + (mrow + mt * 16 + l15) * 32 + quad * 8);
#pragma unroll
    for (int nt = 0; nt < 4; nt++)
      bb[nt] = *(const bf16x8*)(Bs + (ncol + nt * 16 + l15) * 32 + quad * 8);
#pragma unroll
    for (int mt = 0; mt < 4; mt++)
#pragma unroll
      for (int nt = 0; nt < 4; nt++)
        acc[mt][nt] = __builtin_amdgcn_mfma_f32_16x16x32_bf16(
            a[mt], bb[nt], acc[mt][nt], 0, 0, 0);
  }
  if (MODE == 2 && n0 < 1024) {
    unsigned short* O = (unsigned short*)out0;
#pragma unroll
    for (int mt = 0; mt < 4; mt++)
#pragma unroll
      for (int nt = 0; nt < 4; nt++)
#pragma unroll
        for (int r = 0; r < 4; r++) {
          int row = m0 + mrow + mt * 16 + quad * 4 + r;
          int col = n0 + ncol + nt * 16 + l15;
          O[(size_t)row * 1024 + col] = f2bf(acc[mt][nt][r] + bias[col]);
        }
  } else if (MODE == 2) {
    // V blocks: bf16 transposed into vt[(b*512 + (col-1024))*1024 + n]
    __syncthreads();
    unsigned short* buf = (unsigned short*)smem + wave * (64 * 17);
    int b = m0 >> 10, nbase = m0 & 1023;
    for (int nc = 0; nc < 4; nc++) {
#pragma unroll
      for (int mt = 0; mt < 4; mt++)
#pragma unroll
        for (int r = 0; r < 4; r++) {
          int col = n0 + ncol + nc * 16 + l15;
          buf[(mt * 16 + quad * 4 + r) * 17 + l15] = f2bf(acc[mt][nc][r] + bias[col]);
        }
      __syncthreads();
      for (int cc = 0; cc < 16; cc++) {
        int crel = n0 - 1024 + ncol + nc * 16 + cc;
        out1[((size_t)b * C_ + crel) * NSP + nbase + mrow + lane] = buf[lane * 17 + cc];
      }
      __syncthreads();
    }
  } else {
    // MODE 1: fp32 transposed epilogue out0[b][c][n]
    __syncthreads();
    float* buf = (float*)smem + wave * (64 * 17);
    float* O = (float*)out0;
    int b = m0 >> 10, nbase = m0 & 1023;
    for (int nc = 0; nc < 4; nc++) {
#pragma unroll
      for (int mt = 0; mt < 4; mt++)
#pragma unroll
        for (int r = 0; r < 4; r++) {
          int col = n0 + ncol + nc * 16 + l15;
          buf[(mt * 16 + quad * 4 + r) * 17 + l15] = acc[mt][nc][r] + bias[col];
        }
      __syncthreads();
      for (int cc = 0; cc < 16; cc++) {
        int c = n0 + ncol + nc * 16 + cc;
        O[((size_t)b * C_ + c) * NSP + nbase + mrow + lane] = buf[lane * 17 + cc];
      }
      __syncthreads();
    }
  }
}

// ------------------------------------------------------- flash attention
// qk: [b*n][1024] bf16 (Q cols 0-511, K cols 512-1023); vt: [b*512+h*64+d][n]
// block = (b,h, 64 q-rows), 2 waves x 32 q-rows -> grid 1024 blocks
// (5 blocks/CU by LDS; was grid-limited to 2 at q-tile 128).
// S computed TRANSPOSED (S^T = K.Q^T): softmax rows on fixed l15 lanes,
// O accumulated transposed (O^T = V^T.P^T). Softmax in base-2 domain.
__global__ __launch_bounds__(128, 4) void attn_kernel(
    const unsigned short* __restrict__ qk,
    const unsigned short* __restrict__ vt,
    unsigned short* __restrict__ o_ws) {
  __shared__ __align__(16) unsigned short Ks[64][72];
  __shared__ __align__(16) unsigned short Vts[64][72];   // [d][key]
  __shared__ __align__(16) unsigned short Ps[2][32][72]; // per-wave P[m][n]
  int tid = threadIdx.x;
  int wave = tid >> 6, lane = tid & 63, quad = lane >> 4, l15 = lane & 15;
  int b = blockIdx.x >> 3, h = blockIdx.x & 7;
  int q0 = blockIdx.y * 64 + wave * 32;
  // Q fragments straight from global (B-operand layout: rows m, k=d)
  bf16x8 bq[2][2];
#pragma unroll
  for (int mt = 0; mt < 2; mt++)
#pragma unroll
    for (int ks = 0; ks < 2; ks++)
      bq[mt][ks] = *(const bf16x8*)(
          qk + (size_t)(b * NSP + q0 + mt * 16 + l15) * 1024 +
          h * 64 + ks * 32 + quad * 8);
  f32x4 ot[4][2] = {};     // O^T: [d = dt*16+quad*4+r][m = mt*16+l15]
  float mrow[2] = {-INFINITY, -INFINITY}, lrow[2] = {0.f, 0.f};
  for (int kb = 0; kb < NSP / 64; kb++) {
    int k0 = kb * 64;
    if (kb) __syncthreads();
#pragma unroll
    for (int j = 0; j < 4; j++) {     // stage K tile [key][d]
      int idx = tid + 128 * j, row = idx >> 3, c = (idx & 7) * 8;
      *(uint4*)(&Ks[row][c]) = *(const uint4*)(
          qk + (size_t)(b * NSP + k0 + row) * 1024 + 512 + h * 64 + c);
    }
#pragma unroll
    for (int j = 0; j < 4; j++) {     // stage V^T tile [d][key]
      int idx = tid + 128 * j, row = idx >> 3, c = (idx & 7) * 8;
      *(uint4*)(&Vts[row][c]) = *(const uint4*)(
          vt + ((size_t)(b * C_ + h * 64 + row)) * NSP + k0 + c);
    }
    __syncthreads();
    // S^T[n][m] = mfma(A=K rows n, B=Q rows m)
    bf16x8 ak[4][2];
#pragma unroll
    for (int n4 = 0; n4 < 4; n4++)
#pragma unroll
      for (int ks = 0; ks < 2; ks++)
        ak[n4][ks] = *(const bf16x8*)(&Ks[n4 * 16 + l15][ks * 32 + quad * 8]);
    f32x4 s[4][2] = {};
#pragma unroll
    for (int n4 = 0; n4 < 4; n4++)
#pragma unroll
      for (int mt = 0; mt < 2; mt++)
#pragma unroll
        for (int ks = 0; ks < 2; ks++)
          s[n4][mt] = __builtin_amdgcn_mfma_f32_16x16x32_bf16(
              ak[n4][ks], bq[mt][ks], s[n4][mt], 0, 0, 0);
    // online softmax in base-2 domain: row m = mt*16+l15
#pragma unroll
    for (int mt = 0; mt < 2; mt++) {
      float mx = s[0][mt][0];
#pragma unroll
      for (int n4 = 0; n4 < 4; n4++)
#pragma unroll
        for (int r = 0; r < 4; r++) mx = fmaxf(mx, s[n4][mt][r]);
      mx = fmaxf(mx, __shfl_xor(mx, 16));
      mx = fmaxf(mx, __shfl_xor(mx, 32));
      mx *= S2L_;
      float mn = fmaxf(mrow[mt], mx);
      float alpha = __builtin_amdgcn_exp2f(mrow[mt] - mn);
      mrow[mt] = mn;
      float ps = 0.f;
#pragma unroll
      for (int n4 = 0; n4 < 4; n4++)
#pragma unroll
        for (int r = 0; r < 4; r++) {
          float p = __builtin_amdgcn_exp2f(fmaf(s[n4][mt][r], S2L_, -mn));
          s[n4][mt][r] = p;
          ps += p;
        }
      ps += __shfl_xor(ps, 16);
      ps += __shfl_xor(ps, 32);
      lrow[mt] = lrow[mt] * alpha + ps;
#pragma unroll
      for (int dt = 0; dt < 4; dt++) ot[dt][mt] *= alpha;
    }
    // P spill: 4 consecutive n per lane -> b64 writes (wave-private, no barrier)
#pragma unroll
    for (int mt = 0; mt < 2; mt++)
#pragma unroll
      for (int n4 = 0; n4 < 4; n4++) {
        unsigned int lo = (unsigned int)f2bf(s[n4][mt][0]) |
                          ((unsigned int)f2bf(s[n4][mt][1]) << 16);
        unsigned int hi = (unsigned int)f2bf(s[n4][mt][2]) |
                          ((unsigned int)f2bf(s[n4][mt][3]) << 16);
        *(uint2*)(&Ps[wave][mt * 16 + l15][n4 * 16 + quad * 4]) = make_uint2(lo, hi);
      }
    // O^T += mfma(A=V^T rows d, B=P rows m)
    bf16x8 av[4][2], bp[2][2];
#pragma unroll
    for (int dt = 0; dt < 4; dt++)
#pragma unroll
      for (int ks = 0; ks < 2; ks++)
        av[dt][ks] = *(const bf16x8*)(&Vts[dt * 16 + l15][ks * 32 + quad * 8]);
#pragma unroll
    for (int mt = 0; mt < 2; mt++)
#pragma unroll
      for (int ks = 0; ks < 2; ks++)
        bp[mt][ks] = *(const bf16x8*)(&Ps[wave][mt * 16 + l15][ks * 32 + quad * 8]);
#pragma unroll
    for (int dt = 0; dt < 4; dt++)
#pragma unroll
      for (int mt = 0; mt < 2; mt++)
#pragma unroll
        for (int ks = 0; ks < 2; ks++)
          ot[dt][mt] = __builtin_amdgcn_mfma_f32_16x16x32_bf16(
              av[dt][ks], bp[mt][ks], ot[dt][mt], 0, 0, 0);
  }
  // epilogue: o_ws[(b*N+m)*512 + h*64 + d] = O^T[d][m] / l[m]
#pragma unroll
  for (int mt = 0; mt < 2; mt++) {
    float inv = 1.f / lrow[mt];
    size_t rowoff = (size_t)(b * NSP + q0 + mt * 16 + l15) * 512 + h * 64;
#pragma unroll
    for (int dt = 0; dt < 4; dt++) {
      unsigned int lo = (unsigned int)f2bf(ot[dt][mt][0] * inv) |
                        ((unsigned int)f2bf(ot[dt][mt][1] * inv) << 16);
      unsigned int hi = (unsigned int)f2bf(ot[dt][mt][2] * inv) |
                        ((unsigned int)f2bf(ot[dt][mt][3] * inv) << 16);
      *(uint2*)(o_ws + rowoff + dt * 16 + quad * 4) = make_uint2(lo, hi);
    }
  }
}

// ------------------------------------------------------------------ launch
extern "C" void kernel_launch(void* const* d_in, const int* in_sizes, int n_in,
                              void* d_out, int out_size, void* d_ws, size_t ws_size,
                              hipStream_t stream) {
  const float* x     = (const float*)d_in[0];
  const float* gamma = (const float*)d_in[1];
  const float* beta  = (const float*)d_in[2];
  const float* wqkv  = (const float*)d_in[3];
  const float* bqkv  = (const float*)d_in[4];
  const float* wproj = (const float*)d_in[5];
  const float* bproj = (const float*)d_in[6];
  char* ws = (char*)d_ws;
  // workspace layout (35.7 MB total; o_bf aliases xn_bf — xn dead after QKV GEMM)
  float*          mean   = (float*)ws;                        //  32 KB
  float*          rstd   = (float*)(ws + 32768);              //  32 KB
  unsigned short* wqkvT  = (unsigned short*)(ws + 65536);     // 1.5 MB
  unsigned short* wprojT = (unsigned short*)(ws + 1638400);   // 0.5 MB
  unsigned short* qk_bf  = (unsigned short*)(ws + 2162688);   //  16 MB [m][1024]
  unsigned short* vt_bf  = (unsigned short*)(ws + 18939904);  //   8 MB [b*512+c][n]
  unsigned short* xn_bf  = (unsigned short*)(ws + 27328512);  //   8 MB
  unsigned short* o_bf   = xn_bf;                             //   8 MB (alias)
  float* out = (float*)d_out;

  ln_stats_kernel<<<256, 256, 0, stream>>>(x, mean, rstd);
  conv_w_kernel<<<4096, 256, 0, stream>>>(wqkv, wproj, wqkvT, wprojT);
  ln_apply_kernel<<<dim3(8, 16, 8), 256, 0, stream>>>(x, mean, rstd, gamma, beta, xn_bf);
  gemm_kernel<NQKV, 2><<<dim3(NQKV / 128, M_ / 128), 256, 0, stream>>>(
      xn_bf, wqkvT, bqkv, (void*)qk_bf, vt_bf);
  attn_kernel<<<dim3(B_ * NH_, NSP / 64), 128, 0, stream>>>(qk_bf, vt_bf, o_bf);
  gemm_kernel<C_, 1><<<dim3(C_ / 128, M_ / 128), 256, 0, stream>>>(
      o_bf, wprojT, bproj, (void*)out, nullptr);
}